// Round 9
// baseline (174.061 us; speedup 1.0000x reference)
//
#include <hip/hip_runtime.h>
#include <stdint.h>
#include <stddef.h>

// ---------------- types ----------------
typedef __bf16 bf16_t;
typedef bf16_t bf16x4v __attribute__((ext_vector_type(4)));
typedef bf16_t bf16x8v __attribute__((ext_vector_type(8)));
typedef float  f32x4   __attribute__((ext_vector_type(4)));

#define NBATCH 8
#define SEQ    2048
#define DIM    512
#define SP     2052   // padded seq (mult of 12)
#define NB2    1026
#define NB3    684
#define NB4    513
#define NL     512    // output rows per batch (SEQ/4)

static __device__ __forceinline__ f32x4 ldbf4(const bf16_t* p) {
  bf16x4v v = *(const bf16x4v*)p;
  f32x4 r;
  r.x = (float)v[0]; r.y = (float)v[1]; r.z = (float)v[2]; r.w = (float)v[3];
  return r;
}
static __device__ __forceinline__ void stbf4(bf16_t* p, f32x4 v) {
  bf16x4v o;
  o[0] = (bf16_t)v.x; o[1] = (bf16_t)v.y; o[2] = (bf16_t)v.z; o[3] = (bf16_t)v.w;
  *(bf16x4v*)p = o;
}

static __device__ __forceinline__ void gload_lds16(const void* g, void* l) {
  __builtin_amdgcn_global_load_lds(
      (const __attribute__((address_space(1))) void*)g,
      (__attribute__((address_space(3))) void*)l, 16, 0, 0);
}

// ---------------- kPrep: Wt transpose + mask + A'=emb.dw + bias2 --------
// G-trick: H[s] = sum_t G[x[s+t]+256t] + bias2, where
//   G = A' @ pw  with A'[v+256t, d] = emb[v,d]*dw_w[t,d]  (1024x512)
//   bias2[e] = sum_d dwb[d]*pw[d,e] + pwb[e]
#define GP_WT   256                        // 32x32 transpose tiles
#define GP_MASK 65                         // ceil(8*2052/256)
#define GP_AP   512                        // 1024 A' rows, 2 per block
#define GP_B2   2                          // 512 bias2 cols, 256 per block
__global__ __launch_bounds__(256) void kPrep(
    const float* __restrict__ pw, bf16_t* __restrict__ Wt,
    const void* __restrict__ mraw, float* __restrict__ mask01,
    const float* __restrict__ emb, const float* __restrict__ dww,
    const float* __restrict__ dwb, const float* __restrict__ pwb,
    bf16_t* __restrict__ Ap, float* __restrict__ bias2) {
  const int bx = blockIdx.x, t = threadIdx.x;
  if (bx < GP_WT) {
    __shared__ float T[32][33];
    int ti = bx >> 4, tj = bx & 15;
    int r = t >> 3, c0 = (t & 7) * 4;
    f32x4 v = *(const f32x4*)(pw + (size_t)(ti * 32 + r) * DIM + tj * 32 + c0);
    T[c0 + 0][r] = v.x; T[c0 + 1][r] = v.y;
    T[c0 + 2][r] = v.z; T[c0 + 3][r] = v.w;
    __syncthreads();
    bf16x4v o;
    o[0] = (bf16_t)T[r][c0 + 0]; o[1] = (bf16_t)T[r][c0 + 1];
    o[2] = (bf16_t)T[r][c0 + 2]; o[3] = (bf16_t)T[r][c0 + 3];
    *(bf16x4v*)(Wt + (size_t)(tj * 32 + r) * DIM + ti * 32 + c0) = o;
    return;
  }
  if (bx < GP_WT + GP_MASK) {
    int idx = (bx - GP_WT) * 256 + t;
    if (idx >= NBATCH * SP) return;
    int b = idx / SP, s = idx - b * SP;
    const unsigned char* mb = (const unsigned char*)mraw;
    int u8 = 0;
#pragma unroll
    for (int i = 0; i < 64; i++)
      if ((i & 3) != 0 && mb[i] != 0) u8 = 1;
    float v = 0.f;
    if (s < SEQ) {
      int mi = b * SEQ + s;
      int nz = u8 ? (mb[mi] != 0) : (((const int*)mraw)[mi] != 0);
      v = nz ? 1.f : 0.f;
    }
    mask01[idx] = v;
    return;
  }
  if (bx < GP_WT + GP_MASK + GP_AP) {
    int rp = bx - (GP_WT + GP_MASK);
    int row = rp * 2 + (t >> 7);           // 0..1023 = v + 256*t
    int v = row & 255, tt = row >> 8;
    int d0 = (t & 127) * 4;
    f32x4 e = *(const f32x4*)(emb + (size_t)v * DIM + d0);
    f32x4 w = *(const f32x4*)(dww + tt * DIM + d0);
    stbf4(Ap + (size_t)row * DIM + d0, e * w);
    return;
  }
  // bias2
  {
    int e = (bx - (GP_WT + GP_MASK + GP_AP)) * 256 + t;  // 0..511
    float acc = pwb[e];
#pragma unroll 8
    for (int d = 0; d < DIM; d++) acc += dwb[d] * pw[(size_t)d * DIM + e];
    bias2[e] = acc;
  }
}

// ---------------- kG: G = A'(1024x512) @ Wt^T (bf16 MFMA), no bias ------
#define BM 64
#define BN 128
#define BK 32
__global__ __launch_bounds__(256) void kG_gemm(
    const bf16_t* __restrict__ A, const bf16_t* __restrict__ Bt,
    bf16_t* __restrict__ G) {
  __shared__ __align__(16) bf16_t As[BM * BK];
  __shared__ __align__(16) bf16_t Bs[BN * BK];
  const int t = threadIdx.x;
  const int mt = blockIdx.x >> 2, nt = blockIdx.x & 3;   // 16 x 4 tiles
  const int m0 = mt * BM, n0 = nt * BN;
  const int lane = t & 63, wave = t >> 6;
  const int wm = (wave & 1) * 32, wn = (wave >> 1) * 64;
  const int mloc = lane & 15, quad = lane >> 4;

  f32x4 acc[2][4] = {};

  char* asd  = (char*)As + t * 16;
  char* bsd1 = (char*)Bs + t * 16;
  char* bsd2 = (char*)Bs + (t + 256) * 16;
  const int ar = t >> 2, ak = (t & 3) * 8;
  const int br2 = (t + 256) >> 2;

  for (int k0 = 0; k0 < 512; k0 += BK) {
    gload_lds16(A + (size_t)(m0 + ar) * DIM + k0 + ak, asd);
    gload_lds16(Bt + (size_t)(n0 + ar) * DIM + k0 + ak, bsd1);
    gload_lds16(Bt + (size_t)(n0 + br2) * DIM + k0 + ak, bsd2);
    __syncthreads();
    bf16x8v af[2], bfr[4];
#pragma unroll
    for (int i = 0; i < 2; i++)
      af[i] = *(const bf16x8v*)&As[(wm + i * 16 + mloc) * BK + quad * 8];
#pragma unroll
    for (int i = 0; i < 4; i++)
      bfr[i] = *(const bf16x8v*)&Bs[(wn + i * 16 + mloc) * BK + quad * 8];
#pragma unroll
    for (int mi = 0; mi < 2; mi++)
#pragma unroll
      for (int ni = 0; ni < 4; ni++)
        acc[mi][ni] = __builtin_amdgcn_mfma_f32_16x16x32_bf16(
            af[mi], bfr[ni], acc[mi][ni], 0, 0, 0);
    __syncthreads();
  }
#pragma unroll
  for (int ni = 0; ni < 4; ni++) {
    int col = n0 + wn + ni * 16 + mloc;
#pragma unroll
    for (int mi = 0; mi < 2; mi++) {
      int rbase = m0 + wm + mi * 16 + quad * 4;
#pragma unroll
      for (int r = 0; r < 4; r++)
        G[(size_t)(rbase + r) * DIM + col] = (bf16_t)acc[mi][ni][r];
    }
  }
}

// ---- kBH: build H rows from G-gather + level means + score softmax -> P
__global__ __launch_bounds__(128) void kBH_levels(
    const int* __restrict__ x, const bf16_t* __restrict__ G,
    const float* __restrict__ bias2, const float* __restrict__ mask01,
    const float* __restrict__ sw, const float* __restrict__ sbp,
    bf16_t* __restrict__ R2, bf16_t* __restrict__ R3, bf16_t* __restrict__ R4,
    float* __restrict__ P) {
  const int b = blockIdx.x, c = blockIdx.y;   // c: 0..170
  const int s0 = c * 12;
  const int t = threadIdx.x;
  const int d0 = t * 4;
  const float sb = sbp[0];
  __shared__ int xs[15];
  if (t < 15) {
    int sidx = s0 + t;
    xs[t] = (sidx < SEQ) ? x[b * SEQ + sidx] : -1;
  }
  __syncthreads();

  f32x4 b2 = *(const f32x4*)(bias2 + d0);
  f32x4 h[12];
  float ms[12], p[12];
  f32x4 swv = *(const f32x4*)(sw + d0);
#pragma unroll
  for (int i = 0; i < 12; i++) {
    int s = s0 + i;
    ms[i] = mask01[b * SP + s];
    if (s < SEQ) {
      f32x4 acc = b2;
#pragma unroll
      for (int tt = 0; tt < 4; tt++) {
        int xv = xs[i + tt];
        if (xv >= 0)
          acc += ldbf4(G + (size_t)(xv + 256 * tt) * DIM + d0);
      }
      h[i] = acc;
    } else {
      h[i].x = h[i].y = h[i].z = h[i].w = 0.f;
    }
    p[i] = h[i].x * swv.x + h[i].y * swv.y + h[i].z * swv.z + h[i].w * swv.w;
  }
#pragma unroll
  for (int j = 0; j < 6; j++) {
    int i0 = 2 * j;
    float cc = ms[i0] + ms[i0 + 1];
    f32x4 sm = h[i0] * ms[i0] + h[i0 + 1] * ms[i0 + 1];
    float sc = cc > 0.f ? 1.f / cc : 0.f;
    stbf4(R2 + ((size_t)b * NB2 + (c * 6 + j)) * DIM + d0, sm * sc);
  }
#pragma unroll
  for (int j = 0; j < 4; j++) {
    int i0 = 3 * j;
    float cc = ms[i0] + ms[i0 + 1] + ms[i0 + 2];
    f32x4 sm = h[i0] * ms[i0] + h[i0 + 1] * ms[i0 + 1] + h[i0 + 2] * ms[i0 + 2];
    float sc = cc > 0.f ? 1.f / cc : 0.f;
    stbf4(R3 + ((size_t)b * NB3 + (c * 4 + j)) * DIM + d0, sm * sc);
  }
#pragma unroll
  for (int j = 0; j < 3; j++) {
    int i0 = 4 * j;
    float cc = ms[i0] + ms[i0 + 1] + ms[i0 + 2] + ms[i0 + 3];
    f32x4 sm = h[i0] * ms[i0] + h[i0 + 1] * ms[i0 + 1] +
               h[i0 + 2] * ms[i0 + 2] + h[i0 + 3] * ms[i0 + 3];
    float sc = cc > 0.f ? 1.f / cc : 0.f;
    stbf4(R4 + ((size_t)b * NB4 + (c * 3 + j)) * DIM + d0, sm * sc);
  }
#pragma unroll
  for (int off = 32; off > 0; off >>= 1)
#pragma unroll
    for (int i = 0; i < 12; i++) p[i] += __shfl_down(p[i], off);
  __shared__ float hsw[2][12];
  int lane = t & 63, wv = t >> 6;
  if (lane == 0)
#pragma unroll
    for (int i = 0; i < 12; i++) hsw[wv][i] = p[i];
  __syncthreads();
#define HSUM(i) (hsw[0][i] + hsw[1][i])
  if (t < 12) {
    int i = t;
    float m1 = ms[i];
    float v1 = HSUM(i) * m1 + sb;
    int i2 = i & ~1;
    float cc2 = ms[i2] + ms[i2 + 1];
    float s2 = HSUM(i2) * ms[i2] + HSUM(i2 + 1) * ms[i2 + 1];
    float v2 = (cc2 > 0.f ? s2 / cc2 : 0.f) + sb;
    int i3 = (i >= 9) ? 9 : (i >= 6) ? 6 : (i >= 3) ? 3 : 0;
    float cc3 = ms[i3] + ms[i3 + 1] + ms[i3 + 2];
    float s3 = HSUM(i3) * ms[i3] + HSUM(i3 + 1) * ms[i3 + 1] +
               HSUM(i3 + 2) * ms[i3 + 2];
    float v3 = (cc3 > 0.f ? s3 / cc3 : 0.f) + sb;
    int i4 = i & ~3;
    float cc4 = ms[i4] + ms[i4 + 1] + ms[i4 + 2] + ms[i4 + 3];
    float s4 = HSUM(i4) * ms[i4] + HSUM(i4 + 1) * ms[i4 + 1] +
               HSUM(i4 + 2) * ms[i4 + 2] + HSUM(i4 + 3) * ms[i4 + 3];
    float v4 = (cc4 > 0.f ? s4 / cc4 : 0.f) + sb;
    const float NEG = -3.0e38f;
    float a1 = m1 > 0.f ? v1 : NEG, a2 = cc2 > 0.f ? v2 : NEG;
    float a3 = cc3 > 0.f ? v3 : NEG, a4 = cc4 > 0.f ? v4 : NEG;
    float mx = fmaxf(fmaxf(a1, a2), fmaxf(a3, a4));
    f32x4 o;
    if (mx <= NEG) {
      o.x = o.y = o.z = o.w = 0.25f;
    } else {
      float e1 = m1 > 0.f ? __expf(v1 - mx) : 0.f;
      float e2 = cc2 > 0.f ? __expf(v2 - mx) : 0.f;
      float e3 = cc3 > 0.f ? __expf(v3 - mx) : 0.f;
      float e4 = cc4 > 0.f ? __expf(v4 - mx) : 0.f;
      float inv = 1.f / (e1 + e2 + e3 + e4);
      o.x = e1 * inv; o.y = e2 * inv; o.z = e3 * inv; o.w = e4 * inv;
    }
    *(f32x4*)(P + ((size_t)b * SP + s0 + i) * 4) = o;
  }
#undef HSUM
}

// ---- k56: fused seq attention + output; r1 recomputed from G-gather ----
__global__ __launch_bounds__(256) void k56_attn_out(
    const float* __restrict__ P, const float* __restrict__ mask01,
    const int* __restrict__ x, const bf16_t* __restrict__ G,
    const float* __restrict__ bias2, const bf16_t* __restrict__ R2,
    const bf16_t* __restrict__ R3, const bf16_t* __restrict__ R4,
    float* __restrict__ out, float* __restrict__ omask) {
  __shared__ float Px[SP], Py[SP], Pz[SP], Pw[SP];
  __shared__ f32x4 ws4[32];
  __shared__ float msk[32];
  __shared__ float c4w[4];
  __shared__ int xs[35];
  const int b = blockIdx.x, lbase = blockIdx.y * 8;   // 8 l's per block
  const int t = threadIdx.x;
  const int w = t >> 6, lane = t & 63;
  const int smin = lbase * 4;

  if (t < 35) {
    int sidx = smin + t;
    xs[t] = (sidx < SEQ) ? x[b * SEQ + sidx] : -1;
  }
  // stage P[b] rows; zero masked rows (exp(0)=1, corrected via den -= nmask)
  float cnt0 = 0.f;
  for (int j = t; j < SP; j += 256) {
    f32x4 q = *(const f32x4*)(P + ((size_t)b * SP + j) * 4);
    float mf = mask01[b * SP + j];
    if (mf == 0.f) {
      q.x = q.y = q.z = q.w = 0.f;
      cnt0 += 1.f;
    }
    Px[j] = q.x; Py[j] = q.y; Pz[j] = q.z; Pw[j] = q.w;
  }
#pragma unroll
  for (int off = 32; off > 0; off >>= 1) cnt0 += __shfl_down(cnt0, off);
  if (lane == 0) c4w[w] = cnt0;
  __syncthreads();
  const float nmv = c4w[0] + c4w[1] + c4w[2] + c4w[3];

  // attention: wave w handles s-rows [smin + w*8, +8)
#pragma unroll 1
  for (int k = 0; k < 8; k++) {
    int sl = w * 8 + k;                    // 0..31 local s index
    int s = smin + sl;
    float qx = Px[s], qy = Py[s], qz = Pz[s], qw = Pw[s];
    float ax = 0.f, ay = 0.f, az = 0.f, aw = 0.f, den = 0.f;
    for (int j = lane; j < SP; j += 64) {
      float px = Px[j], py = Py[j], pz = Pz[j], pw4 = Pw[j];
      float e = __expf(qx * px + qy * py + qz * pz + qw * pw4);
      den += e;
      ax += e * px; ay += e * py; az += e * pz; aw += e * pw4;
    }
#pragma unroll
    for (int off = 32; off > 0; off >>= 1) {
      ax += __shfl_down(ax, off); ay += __shfl_down(ay, off);
      az += __shfl_down(az, off); aw += __shfl_down(aw, off);
      den += __shfl_down(den, off);
    }
    if (lane == 0) {
      den -= nmv;
      float inv = den > 0.f ? 1.f / den : 0.f;
      f32x4 wv4; wv4.x = ax * inv; wv4.y = ay * inv;
      wv4.z = az * inv; wv4.w = aw * inv;
      ws4[sl] = wv4;
      msk[sl] = mask01[b * SP + s];
    }
  }
  __syncthreads();

  // output: 8 l's, 2 per pass (128 threads each); r1 from G-gather
  const int d0 = (t & 127) * 4;
  const f32x4 b2 = *(const f32x4*)(bias2 + d0);
#pragma unroll 1
  for (int p = 0; p < 4; p++) {
    int ll = p * 2 + (t >> 7);             // local l 0..7
    int l = lbase + ll;
    f32x4 o; o.x = o.y = o.z = o.w = 0.f;
    float cnt = 0.f;
#pragma unroll
    for (int si = 0; si < 4; si++) {
      int sl = ll * 4 + si;
      int s = l * 4 + si;
      float m = msk[sl];
      f32x4 wv4 = ws4[sl];
      f32x4 r1 = b2;
#pragma unroll
      for (int tt = 0; tt < 4; tt++) {
        int xv = xs[sl + tt];
        if (xv >= 0)
          r1 += ldbf4(G + (size_t)(xv + 256 * tt) * DIM + d0);
      }
      f32x4 r2 = ldbf4(R2 + ((size_t)b * NB2 + (s >> 1)) * DIM + d0);
      f32x4 r3 = ldbf4(R3 + ((size_t)b * NB3 + (s / 3)) * DIM + d0);
      f32x4 r4 = ldbf4(R4 + ((size_t)b * NB4 + (s >> 2)) * DIM + d0);
      o += m * (wv4.x * r1 + wv4.y * r2 + wv4.z * r3 + wv4.w * r4);
      cnt += m;
    }
    float inv = cnt > 0.f ? 1.f / cnt : 0.f;
    o *= inv;
    *(f32x4*)(out + ((size_t)b * NL + l) * DIM + d0) = o;
    if ((t & 127) == 0) omask[b * NL + l] = cnt > 0.f ? 1.f : 0.f;
  }
}

// ---------------- launch ----------------
extern "C" void kernel_launch(void* const* d_in, const int* in_sizes, int n_in,
                              void* d_out, int out_size, void* d_ws, size_t ws_size,
                              hipStream_t stream) {
  const int*   x    = (const int*)d_in[0];
  const void*  mraw = d_in[1];
  const float* emb  = (const float*)d_in[2];
  const float* dww  = (const float*)d_in[3];
  const float* dwb  = (const float*)d_in[4];
  const float* pw   = (const float*)d_in[5];
  const float* pwb  = (const float*)d_in[6];
  const float* sw   = (const float*)d_in[7];
  const float* sb   = (const float*)d_in[8];

  char* ws = (char*)d_ws;
  size_t off = 0;
  auto alloc = [&](size_t bytes) {
    size_t o = off;
    off = (off + bytes + 255) & ~(size_t)255;
    return o;
  };
  bf16_t* Ap   = (bf16_t*)(ws + alloc((size_t)1024 * DIM * 2));
  bf16_t* G    = (bf16_t*)(ws + alloc((size_t)1024 * DIM * 2));
  bf16_t* Wt   = (bf16_t*)(ws + alloc((size_t)DIM * DIM * 2));
  float* bias2 = (float*)(ws + alloc((size_t)DIM * 4));
  bf16_t* R2   = (bf16_t*)(ws + alloc((size_t)NBATCH * NB2 * DIM * 2));
  bf16_t* R3   = (bf16_t*)(ws + alloc((size_t)NBATCH * NB3 * DIM * 2));
  bf16_t* R4   = (bf16_t*)(ws + alloc((size_t)NBATCH * NB4 * DIM * 2));
  float* mask01 = (float*)(ws + alloc((size_t)NBATCH * SP * 4));
  float* P     = (float*)(ws + alloc((size_t)NBATCH * SP * 4 * 4));

  float* out   = (float*)d_out;
  float* omask = out + (size_t)NBATCH * NL * DIM;

  kPrep<<<GP_WT + GP_MASK + GP_AP + GP_B2, 256, 0, stream>>>(
      pw, Wt, mraw, mask01, emb, dww, dwb, pwb, Ap, bias2);
  kG_gemm<<<64, 256, 0, stream>>>(Ap, Wt, G);
  kBH_levels<<<dim3(NBATCH, 171), 128, 0, stream>>>(x, G, bias2, mask01,
                                                    sw, sb, R2, R3, R4, P);
  k56_attn_out<<<dim3(NBATCH, 64), 256, 0, stream>>>(P, mask01, x, G, bias2,
                                                     R2, R3, R4, out, omask);
}

// Round 11
// 161.444 us; speedup vs baseline: 1.0782x; 1.0782x over previous
//
#include <hip/hip_runtime.h>
#include <stdint.h>
#include <stddef.h>

// ---------------- types ----------------
typedef __bf16 bf16_t;
typedef bf16_t bf16x4v __attribute__((ext_vector_type(4)));
typedef bf16_t bf16x8v __attribute__((ext_vector_type(8)));
typedef float  f32x4   __attribute__((ext_vector_type(4)));

#define NBATCH 8
#define SEQ    2048
#define DIM    512
#define SP     2052   // padded seq (mult of 12)
#define NB2    1026
#define NB3    684
#define NB4    513
#define NL     512    // output rows per batch (SEQ/4)

static __device__ __forceinline__ f32x4 ldbf4(const bf16_t* p) {
  bf16x4v v = *(const bf16x4v*)p;
  f32x4 r;
  r.x = (float)v[0]; r.y = (float)v[1]; r.z = (float)v[2]; r.w = (float)v[3];
  return r;
}
static __device__ __forceinline__ void stbf4(bf16_t* p, f32x4 v) {
  bf16x4v o;
  o[0] = (bf16_t)v.x; o[1] = (bf16_t)v.y; o[2] = (bf16_t)v.z; o[3] = (bf16_t)v.w;
  *(bf16x4v*)p = o;
}

static __device__ __forceinline__ void gload_lds16(const void* g, void* l) {
  __builtin_amdgcn_global_load_lds(
      (const __attribute__((address_space(1))) void*)g,
      (__attribute__((address_space(3))) void*)l, 16, 0, 0);
}

// ---------------- kPrep: Wt transpose + mask + A'=emb.dw + bias2 --------
// G-trick: H[s] = sum_t G[x[s+t]+256t] + bias2, where
//   G = A' @ pw  with A'[v+256t, d] = emb[v,d]*dw_w[t,d]  (1024x512)
//   bias2[e] = sum_d dwb[d]*pw[d,e] + pwb[e]
#define GP_WT   256                        // 32x32 transpose tiles
#define GP_MASK 65                         // ceil(8*2052/256)
#define GP_AP   512                        // 1024 A' rows, 2 per block
#define GP_B2   2                          // 512 bias2 cols, 256 per block
__global__ __launch_bounds__(256) void kPrep(
    const float* __restrict__ pw, bf16_t* __restrict__ Wt,
    const void* __restrict__ mraw, float* __restrict__ mask01,
    const float* __restrict__ emb, const float* __restrict__ dww,
    const float* __restrict__ dwb, const float* __restrict__ pwb,
    bf16_t* __restrict__ Ap, float* __restrict__ bias2) {
  const int bx = blockIdx.x, t = threadIdx.x;
  if (bx < GP_WT) {
    __shared__ float T[32][33];
    int ti = bx >> 4, tj = bx & 15;
    int r = t >> 3, c0 = (t & 7) * 4;
    f32x4 v = *(const f32x4*)(pw + (size_t)(ti * 32 + r) * DIM + tj * 32 + c0);
    T[c0 + 0][r] = v.x; T[c0 + 1][r] = v.y;
    T[c0 + 2][r] = v.z; T[c0 + 3][r] = v.w;
    __syncthreads();
    bf16x4v o;
    o[0] = (bf16_t)T[r][c0 + 0]; o[1] = (bf16_t)T[r][c0 + 1];
    o[2] = (bf16_t)T[r][c0 + 2]; o[3] = (bf16_t)T[r][c0 + 3];
    *(bf16x4v*)(Wt + (size_t)(tj * 32 + r) * DIM + ti * 32 + c0) = o;
    return;
  }
  if (bx < GP_WT + GP_MASK) {
    int idx = (bx - GP_WT) * 256 + t;
    if (idx >= NBATCH * SP) return;
    int b = idx / SP, s = idx - b * SP;
    const unsigned char* mb = (const unsigned char*)mraw;
    int u8 = 0;
#pragma unroll
    for (int i = 0; i < 64; i++)
      if ((i & 3) != 0 && mb[i] != 0) u8 = 1;
    float v = 0.f;
    if (s < SEQ) {
      int mi = b * SEQ + s;
      int nz = u8 ? (mb[mi] != 0) : (((const int*)mraw)[mi] != 0);
      v = nz ? 1.f : 0.f;
    }
    mask01[idx] = v;
    return;
  }
  if (bx < GP_WT + GP_MASK + GP_AP) {
    int rp = bx - (GP_WT + GP_MASK);
    int row = rp * 2 + (t >> 7);           // 0..1023 = v + 256*t
    int v = row & 255, tt = row >> 8;
    int d0 = (t & 127) * 4;
    f32x4 e = *(const f32x4*)(emb + (size_t)v * DIM + d0);
    f32x4 w = *(const f32x4*)(dww + tt * DIM + d0);
    stbf4(Ap + (size_t)row * DIM + d0, e * w);
    return;
  }
  // bias2
  {
    int e = (bx - (GP_WT + GP_MASK + GP_AP)) * 256 + t;  // 0..511
    float acc = pwb[e];
#pragma unroll 8
    for (int d = 0; d < DIM; d++) acc += dwb[d] * pw[(size_t)d * DIM + e];
    bias2[e] = acc;
  }
}

// ---------------- kG: G = A'(1024x512) @ Wt^T (bf16 MFMA), no bias ------
#define BM 64
#define BN 128
#define BK 32
__global__ __launch_bounds__(256) void kG_gemm(
    const bf16_t* __restrict__ A, const bf16_t* __restrict__ Bt,
    bf16_t* __restrict__ G) {
  __shared__ __align__(16) bf16_t As[BM * BK];
  __shared__ __align__(16) bf16_t Bs[BN * BK];
  const int t = threadIdx.x;
  const int mt = blockIdx.x >> 2, nt = blockIdx.x & 3;   // 16 x 4 tiles
  const int m0 = mt * BM, n0 = nt * BN;
  const int lane = t & 63, wave = t >> 6;
  const int wm = (wave & 1) * 32, wn = (wave >> 1) * 64;
  const int mloc = lane & 15, quad = lane >> 4;

  f32x4 acc[2][4] = {};

  char* asd  = (char*)As + t * 16;
  char* bsd1 = (char*)Bs + t * 16;
  char* bsd2 = (char*)Bs + (t + 256) * 16;
  const int ar = t >> 2, ak = (t & 3) * 8;
  const int br2 = (t + 256) >> 2;

  for (int k0 = 0; k0 < 512; k0 += BK) {
    gload_lds16(A + (size_t)(m0 + ar) * DIM + k0 + ak, asd);
    gload_lds16(Bt + (size_t)(n0 + ar) * DIM + k0 + ak, bsd1);
    gload_lds16(Bt + (size_t)(n0 + br2) * DIM + k0 + ak, bsd2);
    __syncthreads();
    bf16x8v af[2], bfr[4];
#pragma unroll
    for (int i = 0; i < 2; i++)
      af[i] = *(const bf16x8v*)&As[(wm + i * 16 + mloc) * BK + quad * 8];
#pragma unroll
    for (int i = 0; i < 4; i++)
      bfr[i] = *(const bf16x8v*)&Bs[(wn + i * 16 + mloc) * BK + quad * 8];
#pragma unroll
    for (int mi = 0; mi < 2; mi++)
#pragma unroll
      for (int ni = 0; ni < 4; ni++)
        acc[mi][ni] = __builtin_amdgcn_mfma_f32_16x16x32_bf16(
            af[mi], bfr[ni], acc[mi][ni], 0, 0, 0);
    __syncthreads();
  }
#pragma unroll
  for (int ni = 0; ni < 4; ni++) {
    int col = n0 + wn + ni * 16 + mloc;
#pragma unroll
    for (int mi = 0; mi < 2; mi++) {
      int rbase = m0 + wm + mi * 16 + quad * 4;
#pragma unroll
      for (int r = 0; r < 4; r++)
        G[(size_t)(rbase + r) * DIM + col] = (bf16_t)acc[mi][ni][r];
    }
  }
}

// ---- kBH: build H rows from G-gather + level means + score softmax -> P
__global__ __launch_bounds__(128) void kBH_levels(
    const int* __restrict__ x, const bf16_t* __restrict__ G,
    const float* __restrict__ bias2, const float* __restrict__ mask01,
    const float* __restrict__ sw, const float* __restrict__ sbp,
    bf16_t* __restrict__ R2, bf16_t* __restrict__ R3, bf16_t* __restrict__ R4,
    float* __restrict__ P) {
  const int b = blockIdx.x, c = blockIdx.y;   // c: 0..170
  const int s0 = c * 12;
  const int t = threadIdx.x;
  const int d0 = t * 4;
  const float sb = sbp[0];
  __shared__ int xs[15];
  if (t < 15) {
    int sidx = s0 + t;
    xs[t] = (sidx < SEQ) ? x[b * SEQ + sidx] : -1;
  }
  __syncthreads();

  f32x4 b2 = *(const f32x4*)(bias2 + d0);
  f32x4 h[12];
  float ms[12], p[12];
  f32x4 swv = *(const f32x4*)(sw + d0);
#pragma unroll
  for (int i = 0; i < 12; i++) {
    int s = s0 + i;
    ms[i] = mask01[b * SP + s];
    if (s < SEQ) {
      f32x4 acc = b2;
#pragma unroll
      for (int tt = 0; tt < 4; tt++) {
        int xv = xs[i + tt];
        if (xv >= 0)
          acc += ldbf4(G + (size_t)(xv + 256 * tt) * DIM + d0);
      }
      h[i] = acc;
    } else {
      h[i].x = h[i].y = h[i].z = h[i].w = 0.f;
    }
    p[i] = h[i].x * swv.x + h[i].y * swv.y + h[i].z * swv.z + h[i].w * swv.w;
  }
#pragma unroll
  for (int j = 0; j < 6; j++) {
    int i0 = 2 * j;
    float cc = ms[i0] + ms[i0 + 1];
    f32x4 sm = h[i0] * ms[i0] + h[i0 + 1] * ms[i0 + 1];
    float sc = cc > 0.f ? 1.f / cc : 0.f;
    stbf4(R2 + ((size_t)b * NB2 + (c * 6 + j)) * DIM + d0, sm * sc);
  }
#pragma unroll
  for (int j = 0; j < 4; j++) {
    int i0 = 3 * j;
    float cc = ms[i0] + ms[i0 + 1] + ms[i0 + 2];
    f32x4 sm = h[i0] * ms[i0] + h[i0 + 1] * ms[i0 + 1] + h[i0 + 2] * ms[i0 + 2];
    float sc = cc > 0.f ? 1.f / cc : 0.f;
    stbf4(R3 + ((size_t)b * NB3 + (c * 4 + j)) * DIM + d0, sm * sc);
  }
#pragma unroll
  for (int j = 0; j < 3; j++) {
    int i0 = 4 * j;
    float cc = ms[i0] + ms[i0 + 1] + ms[i0 + 2] + ms[i0 + 3];
    f32x4 sm = h[i0] * ms[i0] + h[i0 + 1] * ms[i0 + 1] +
               h[i0 + 2] * ms[i0 + 2] + h[i0 + 3] * ms[i0 + 3];
    float sc = cc > 0.f ? 1.f / cc : 0.f;
    stbf4(R4 + ((size_t)b * NB4 + (c * 3 + j)) * DIM + d0, sm * sc);
  }
#pragma unroll
  for (int off = 32; off > 0; off >>= 1)
#pragma unroll
    for (int i = 0; i < 12; i++) p[i] += __shfl_down(p[i], off);
  __shared__ float hsw[2][12];
  int lane = t & 63, wv = t >> 6;
  if (lane == 0)
#pragma unroll
    for (int i = 0; i < 12; i++) hsw[wv][i] = p[i];
  __syncthreads();
#define HSUM(i) (hsw[0][i] + hsw[1][i])
  if (t < 12) {
    int i = t;
    float m1 = ms[i];
    float v1 = HSUM(i) * m1 + sb;
    int i2 = i & ~1;
    float cc2 = ms[i2] + ms[i2 + 1];
    float s2 = HSUM(i2) * ms[i2] + HSUM(i2 + 1) * ms[i2 + 1];
    float v2 = (cc2 > 0.f ? s2 / cc2 : 0.f) + sb;
    int i3 = (i >= 9) ? 9 : (i >= 6) ? 6 : (i >= 3) ? 3 : 0;
    float cc3 = ms[i3] + ms[i3 + 1] + ms[i3 + 2];
    float s3 = HSUM(i3) * ms[i3] + HSUM(i3 + 1) * ms[i3 + 1] +
               HSUM(i3 + 2) * ms[i3 + 2];
    float v3 = (cc3 > 0.f ? s3 / cc3 : 0.f) + sb;
    int i4 = i & ~3;
    float cc4 = ms[i4] + ms[i4 + 1] + ms[i4 + 2] + ms[i4 + 3];
    float s4 = HSUM(i4) * ms[i4] + HSUM(i4 + 1) * ms[i4 + 1] +
               HSUM(i4 + 2) * ms[i4 + 2] + HSUM(i4 + 3) * ms[i4 + 3];
    float v4 = (cc4 > 0.f ? s4 / cc4 : 0.f) + sb;
    const float NEG = -3.0e38f;
    float a1 = m1 > 0.f ? v1 : NEG, a2 = cc2 > 0.f ? v2 : NEG;
    float a3 = cc3 > 0.f ? v3 : NEG, a4 = cc4 > 0.f ? v4 : NEG;
    float mx = fmaxf(fmaxf(a1, a2), fmaxf(a3, a4));
    f32x4 o;
    if (mx <= NEG) {
      o.x = o.y = o.z = o.w = 0.25f;
    } else {
      float e1 = m1 > 0.f ? __expf(v1 - mx) : 0.f;
      float e2 = cc2 > 0.f ? __expf(v2 - mx) : 0.f;
      float e3 = cc3 > 0.f ? __expf(v3 - mx) : 0.f;
      float e4 = cc4 > 0.f ? __expf(v4 - mx) : 0.f;
      float inv = 1.f / (e1 + e2 + e3 + e4);
      o.x = e1 * inv; o.y = e2 * inv; o.z = e3 * inv; o.w = e4 * inv;
    }
    *(f32x4*)(P + ((size_t)b * SP + s0 + i) * 4) = o;
  }
#undef HSUM
}

// ---- k56: fused seq attention + output; r1 recomputed from G-gather ----
// v2: grid (8,128) -> 4 blocks/CU (16 waves/CU); AoS f32x4 LDS with
// 4-way j-unroll (4 independent ds_read_b128 + exp chains per iter) to
// cover LDS latency. LDS padded to LQ=2304 rows (mult of 256); pad rows
// zeroed and counted in nmv (exp(0)=1 correction is exact).
#define LQ 2304
__global__ __launch_bounds__(256) void k56_attn_out(
    const float* __restrict__ P, const float* __restrict__ mask01,
    const int* __restrict__ x, const bf16_t* __restrict__ G,
    const float* __restrict__ bias2, const bf16_t* __restrict__ R2,
    const bf16_t* __restrict__ R3, const bf16_t* __restrict__ R4,
    float* __restrict__ out, float* __restrict__ omask) {
  __shared__ f32x4 Qs[LQ];                 // 36864 B
  __shared__ f32x4 ws4[16];
  __shared__ float msk[16];
  __shared__ float c4w[4];
  __shared__ int xs[20];
  const int b = blockIdx.x, lbase = blockIdx.y * 4;   // 4 l's per block
  const int t = threadIdx.x;
  const int w = t >> 6, lane = t & 63;
  const int smin = lbase * 4;              // 16 s-rows per block

  if (t < 20) {
    int sidx = smin + t;
    xs[t] = (sidx < SEQ) ? x[b * SEQ + sidx] : -1;
  }
  // stage P[b]; zero masked + pad rows (counted in nmv)
  float cnt0 = 0.f;
#pragma unroll
  for (int it = 0; it < LQ / 256; it++) {
    int j = it * 256 + t;
    f32x4 q; q.x = q.y = q.z = q.w = 0.f;
    if (j < SP) {
      float mf = mask01[b * SP + j];
      if (mf != 0.f) {
        q = *(const f32x4*)(P + ((size_t)b * SP + j) * 4);
      } else {
        cnt0 += 1.f;
      }
    } else {
      cnt0 += 1.f;
    }
    Qs[j] = q;
  }
#pragma unroll
  for (int off = 32; off > 0; off >>= 1) cnt0 += __shfl_down(cnt0, off);
  if (lane == 0) c4w[w] = cnt0;
  __syncthreads();
  const float nmv = c4w[0] + c4w[1] + c4w[2] + c4w[3];

  // attention: wave w handles rows sl = w*4 .. w*4+3
#pragma unroll 1
  for (int k = 0; k < 4; k++) {
    int sl = w * 4 + k;
    int s = smin + sl;
    f32x4 qi = Qs[s];
    f32x4 ac0, ac1, ac2, ac3;
    ac0.x=ac0.y=ac0.z=ac0.w=0.f; ac1=ac0; ac2=ac0; ac3=ac0;
    float dn0 = 0.f, dn1 = 0.f, dn2 = 0.f, dn3 = 0.f;
#pragma unroll 1
    for (int it = 0; it < LQ / 256; it++) {
      int jb = it * 256 + lane;
      f32x4 p0 = Qs[jb], p1 = Qs[jb + 64], p2 = Qs[jb + 128], p3 = Qs[jb + 192];
      float e0 = __expf(qi.x*p0.x + qi.y*p0.y + qi.z*p0.z + qi.w*p0.w);
      float e1 = __expf(qi.x*p1.x + qi.y*p1.y + qi.z*p1.z + qi.w*p1.w);
      float e2 = __expf(qi.x*p2.x + qi.y*p2.y + qi.z*p2.z + qi.w*p2.w);
      float e3 = __expf(qi.x*p3.x + qi.y*p3.y + qi.z*p3.z + qi.w*p3.w);
      dn0 += e0; ac0 += e0 * p0;
      dn1 += e1; ac1 += e1 * p1;
      dn2 += e2; ac2 += e2 * p2;
      dn3 += e3; ac3 += e3 * p3;
    }
    f32x4 acc = (ac0 + ac1) + (ac2 + ac3);
    float den = (dn0 + dn1) + (dn2 + dn3);
#pragma unroll
    for (int off = 32; off > 0; off >>= 1) {
      acc.x += __shfl_down(acc.x, off);
      acc.y += __shfl_down(acc.y, off);
      acc.z += __shfl_down(acc.z, off);
      acc.w += __shfl_down(acc.w, off);
      den   += __shfl_down(den, off);
    }
    if (lane == 0) {
      den -= nmv;
      float inv = den > 0.f ? 1.f / den : 0.f;
      f32x4 wv4; wv4.x = acc.x * inv; wv4.y = acc.y * inv;
      wv4.z = acc.z * inv; wv4.w = acc.w * inv;
      ws4[sl] = wv4;
      msk[sl] = mask01[b * SP + s];
    }
  }
  __syncthreads();

  // output: 4 l's, 2 per pass (128 threads each); r1 from G-gather
  const int d0 = (t & 127) * 4;
  const f32x4 b2 = *(const f32x4*)(bias2 + d0);
#pragma unroll 1
  for (int p = 0; p < 2; p++) {
    int ll = p * 2 + (t >> 7);             // local l 0..3
    int l = lbase + ll;
    f32x4 o; o.x = o.y = o.z = o.w = 0.f;
    float cnt = 0.f;
#pragma unroll
    for (int si = 0; si < 4; si++) {
      int sl = ll * 4 + si;
      int s = l * 4 + si;
      float m = msk[sl];
      f32x4 wv4 = ws4[sl];
      f32x4 r1 = b2;
#pragma unroll
      for (int tt = 0; tt < 4; tt++) {
        int xv = xs[sl + tt];
        if (xv >= 0)
          r1 += ldbf4(G + (size_t)(xv + 256 * tt) * DIM + d0);
      }
      f32x4 r2 = ldbf4(R2 + ((size_t)b * NB2 + (s >> 1)) * DIM + d0);
      f32x4 r3 = ldbf4(R3 + ((size_t)b * NB3 + (s / 3)) * DIM + d0);
      f32x4 r4 = ldbf4(R4 + ((size_t)b * NB4 + (s >> 2)) * DIM + d0);
      o += m * (wv4.x * r1 + wv4.y * r2 + wv4.z * r3 + wv4.w * r4);
      cnt += m;
    }
    float inv = cnt > 0.f ? 1.f / cnt : 0.f;
    o *= inv;
    *(f32x4*)(out + ((size_t)b * NL + l) * DIM + d0) = o;
    if ((t & 127) == 0) omask[b * NL + l] = cnt > 0.f ? 1.f : 0.f;
  }
}

// ---------------- launch ----------------
extern "C" void kernel_launch(void* const* d_in, const int* in_sizes, int n_in,
                              void* d_out, int out_size, void* d_ws, size_t ws_size,
                              hipStream_t stream) {
  const int*   x    = (const int*)d_in[0];
  const void*  mraw = d_in[1];
  const float* emb  = (const float*)d_in[2];
  const float* dww  = (const float*)d_in[3];
  const float* dwb  = (const float*)d_in[4];
  const float* pw   = (const float*)d_in[5];
  const float* pwb  = (const float*)d_in[6];
  const float* sw   = (const float*)d_in[7];
  const float* sb   = (const float*)d_in[8];

  char* ws = (char*)d_ws;
  size_t off = 0;
  auto alloc = [&](size_t bytes) {
    size_t o = off;
    off = (off + bytes + 255) & ~(size_t)255;
    return o;
  };
  bf16_t* Ap   = (bf16_t*)(ws + alloc((size_t)1024 * DIM * 2));
  bf16_t* G    = (bf16_t*)(ws + alloc((size_t)1024 * DIM * 2));
  bf16_t* Wt   = (bf16_t*)(ws + alloc((size_t)DIM * DIM * 2));
  float* bias2 = (float*)(ws + alloc((size_t)DIM * 4));
  bf16_t* R2   = (bf16_t*)(ws + alloc((size_t)NBATCH * NB2 * DIM * 2));
  bf16_t* R3   = (bf16_t*)(ws + alloc((size_t)NBATCH * NB3 * DIM * 2));
  bf16_t* R4   = (bf16_t*)(ws + alloc((size_t)NBATCH * NB4 * DIM * 2));
  float* mask01 = (float*)(ws + alloc((size_t)NBATCH * SP * 4));
  float* P     = (float*)(ws + alloc((size_t)NBATCH * SP * 4 * 4));

  float* out   = (float*)d_out;
  float* omask = out + (size_t)NBATCH * NL * DIM;

  kPrep<<<GP_WT + GP_MASK + GP_AP + GP_B2, 256, 0, stream>>>(
      pw, Wt, mraw, mask01, emb, dww, dwb, pwb, Ap, bias2);
  kG_gemm<<<64, 256, 0, stream>>>(Ap, Wt, G);
  kBH_levels<<<dim3(NBATCH, 171), 128, 0, stream>>>(x, G, bias2, mask01,
                                                    sw, sb, R2, R3, R4, P);
  k56_attn_out<<<dim3(NBATCH, 128), 256, 0, stream>>>(P, mask01, x, G, bias2,
                                                      R2, R3, R4, out, omask);
}